// Round 8
// baseline (530.727 us; speedup 1.0000x reference)
//
#include <hip/hip_runtime.h>
#include <math.h>

#define NB 4
#define NN 1024
#define NM 1024
#define NC 384
#define NK 10
#define NG 2
#define NGC 192
#define NH 6

#define GSZ ((size_t)NB * NM * NC)   // per-g table size (elements)
#define QSZ ((size_t)NB * NN * NC)
#define NCNC ((size_t)NC * NC)

// Wt_all layout (floats)
#define OFF_WQ 0
#define OFF_W1B 147456
#define OFF_WK0 221184
#define OFF_WK1 294912
#define OFF_WV0 368640
#define OFF_WV1 442368
#define OFF_WPROJ 516096
#define WT_ALL_FLOATS 663552

__device__ __forceinline__ float wred_sum(float v) {
#pragma unroll
  for (int m = 32; m >= 1; m >>= 1) v += __shfl_xor(v, m, 64);
  return v;
}

// lexicographic (d, m) min across 64 lanes; ties -> lower m (matches top_k)
__device__ __forceinline__ void wred_argmin(float& d, int& m) {
#pragma unroll
  for (int off = 32; off >= 1; off >>= 1) {
    float od = __shfl_xor(d, off, 64);
    int om = __shfl_xor(m, off, 64);
    if (od < d || (od == d && om < m)) { d = od; m = om; }
  }
}

__device__ __forceinline__ ushort f2bf(float x) {  // RNE, finite inputs
  unsigned u = __float_as_uint(x);
  unsigned r = (u + 0x7fffu + ((u >> 16) & 1u)) >> 16;
  return (ushort)r;
}
__device__ __forceinline__ float b2f(ushort s) {
  return __uint_as_float(((unsigned)s) << 16);
}

// all 7 weight transposes in one launch; blockIdx.y = job
__global__ void transpose_all_k(const float* __restrict__ Wq, const float* __restrict__ Woff1,
                                const float* __restrict__ Wk, const float* __restrict__ Wv,
                                const float* __restrict__ Wproj, float* __restrict__ Wt_all) {
  const float* W;
  int i0, icount, doff;
  switch (blockIdx.y) {
    case 0: W = Wq;    i0 = 0;   icount = NC;  doff = OFF_WQ;    break;
    case 1: W = Woff1; i0 = NGC; icount = NGC; doff = OFF_W1B;   break;
    case 2: W = Wk;    i0 = 0;   icount = NGC; doff = OFF_WK0;   break;
    case 3: W = Wk;    i0 = NGC; icount = NGC; doff = OFF_WK1;   break;
    case 4: W = Wv;    i0 = 0;   icount = NGC; doff = OFF_WV0;   break;
    case 5: W = Wv;    i0 = NGC; icount = NGC; doff = OFF_WV1;   break;
    default: W = Wproj; i0 = 0;  icount = NC;  doff = OFF_WPROJ; break;
  }
  int id = blockIdx.x * 256 + threadIdx.x;
  if (id >= icount * NC) return;
  int o = id % NC;
  int i = id / NC;
  Wt_all[doff + (size_t)i * NC + o] = W[(size_t)o * NC + i0 + i];
}

// Wcomb_t[g][i][o] = sum_j Woff1[o][j] * Wvoff[g*192+j][i]   (j < 192)
__global__ void wcomb_k(const float* __restrict__ Woff1, const float* __restrict__ Wvoff,
                        float* __restrict__ Wcomb_t) {
  int o = blockIdx.x;
  int g = blockIdx.y;
  int i = threadIdx.x;
  __shared__ float w1[NGC];
  if (i < NGC) w1[i] = Woff1[(size_t)o * NC + i];
  __syncthreads();
  float acc = 0.f;
#pragma unroll 4
  for (int j = 0; j < NGC; ++j)
    acc = fmaf(w1[j], Wvoff[(size_t)(g * NGC + j) * NC + i], acc);
  Wcomb_t[((size_t)g * NC + i) * NC + o] = acc;
}

// generic 16-row 4x4 register-blocked GEMM; blockIdx.y = job
__global__ __launch_bounds__(384) void gemm16_k(const float* __restrict__ X, int IN, int xoff0,
                                                int xoff_stride, const float* __restrict__ Wt0,
                                                size_t wstride, const float* __restrict__ bias,
                                                float* __restrict__ Y0, size_t ystride) {
  __shared__ __align__(16) float xs[NC][20];
  int tid = threadIdx.x;
  int og = tid % 96, rg = tid / 96;
  int r0 = blockIdx.x * 16;
  int job = blockIdx.y;
  int xoff = xoff0 + job * xoff_stride;
  const float* Wt = Wt0 + (size_t)job * wstride;
  float* Y = Y0 + (size_t)job * ystride;
  for (int t = tid; t < 16 * IN; t += 384) {
    int r = t / IN, kk = t % IN;
    xs[kk][r] = X[(size_t)(r0 + r) * NC + xoff + kk];
  }
  __syncthreads();
  float acc[4][4];
#pragma unroll
  for (int i = 0; i < 4; ++i)
#pragma unroll
    for (int j = 0; j < 4; ++j) acc[i][j] = 0.f;
  int o = og * 4;
#pragma unroll 4
  for (int kk = 0; kk < IN; ++kk) {
    float4 w4 = *(const float4*)&Wt[(size_t)kk * NC + o];
    float4 x4 = *(const float4*)&xs[kk][rg * 4];
    float xr[4] = {x4.x, x4.y, x4.z, x4.w};
    float wr[4] = {w4.x, w4.y, w4.z, w4.w};
#pragma unroll
    for (int ri = 0; ri < 4; ++ri)
#pragma unroll
      for (int oi = 0; oi < 4; ++oi) acc[ri][oi] = fmaf(xr[ri], wr[oi], acc[ri][oi]);
  }
  float4 bv = make_float4(0.f, 0.f, 0.f, 0.f);
  if (bias) bv = *(const float4*)&bias[o];
#pragma unroll
  for (int ri = 0; ri < 4; ++ri) {
    float4 ov;
    ov.x = acc[ri][0] + bv.x;
    ov.y = acc[ri][1] + bv.y;
    ov.z = acc[ri][2] + bv.z;
    ov.w = acc[ri][3] + bv.w;
    *(float4*)&Y[(size_t)(r0 + rg * 4 + ri) * NC + o] = ov;
  }
}

// v projections, blockIdx.y = job; jobs 2-5 write bf16
__global__ __launch_bounds__(384) void vproj_k(const float* __restrict__ v,
                                               const float* __restrict__ Wcomb_t,
                                               const float* __restrict__ Wt_all,
                                               float* __restrict__ vcontrib,
                                               ushort* __restrict__ KcT,
                                               ushort* __restrict__ VcT) {
  __shared__ __align__(16) float xs[NC][20];
  int tid = threadIdx.x;
  int og = tid % 96, rg = tid / 96;
  int r0 = blockIdx.x * 16;
  int job = blockIdx.y;
  const float* Wt;
  float* Yf = nullptr;
  ushort* Yh = nullptr;
  int IN, xoff;
  switch (job) {
    case 0: Wt = Wcomb_t;        IN = NC;  xoff = 0;   Yf = vcontrib;       break;
    case 1: Wt = Wcomb_t + NCNC; IN = NC;  xoff = 0;   Yf = vcontrib + GSZ; break;
    case 2: Wt = Wt_all + OFF_WK0; IN = NGC; xoff = 0;   Yh = KcT;          break;
    case 3: Wt = Wt_all + OFF_WK1; IN = NGC; xoff = NGC; Yh = KcT + GSZ;    break;
    case 4: Wt = Wt_all + OFF_WV0; IN = NGC; xoff = 0;   Yh = VcT;          break;
    default: Wt = Wt_all + OFF_WV1; IN = NGC; xoff = NGC; Yh = VcT + GSZ;   break;
  }
  for (int t = tid; t < 16 * IN; t += 384) {
    int r = t / IN, kk = t % IN;
    xs[kk][r] = v[(size_t)(r0 + r) * NC + xoff + kk];
  }
  __syncthreads();
  float acc[4][4];
#pragma unroll
  for (int i = 0; i < 4; ++i)
#pragma unroll
    for (int j = 0; j < 4; ++j) acc[i][j] = 0.f;
  int o = og * 4;
#pragma unroll 4
  for (int kk = 0; kk < IN; ++kk) {
    float4 w4 = *(const float4*)&Wt[(size_t)kk * NC + o];
    float4 x4 = *(const float4*)&xs[kk][rg * 4];
    float xr[4] = {x4.x, x4.y, x4.z, x4.w};
    float wr[4] = {w4.x, w4.y, w4.z, w4.w};
#pragma unroll
    for (int ri = 0; ri < 4; ++ri)
#pragma unroll
      for (int oi = 0; oi < 4; ++oi) acc[ri][oi] = fmaf(xr[ri], wr[oi], acc[ri][oi]);
  }
  if (Yf) {
#pragma unroll
    for (int ri = 0; ri < 4; ++ri)
      *(float4*)&Yf[(size_t)(r0 + rg * 4 + ri) * NC + o] =
          make_float4(acc[ri][0], acc[ri][1], acc[ri][2], acc[ri][3]);
  } else {
#pragma unroll
    for (int ri = 0; ri < 4; ++ri) {
      ushort4 pk;
      pk.x = f2bf(acc[ri][0]);
      pk.y = f2bf(acc[ri][1]);
      pk.z = f2bf(acc[ri][2]);
      pk.w = f2bf(acc[ri][3]);
      *(ushort4*)&Yh[(size_t)(r0 + rg * 4 + ri) * NC + o] = pk;
    }
  }
}

// wave-per-query KNN: lane scans 16 candidates -> register top-10 -> argmin-merge
__global__ __launch_bounds__(256) void knn2_k(const float* __restrict__ q_pos,
                                              const float* __restrict__ v_pos,
                                              int* __restrict__ knn_idx) {
  __shared__ float4 cpos[NM];
  int tid = threadIdx.x, lane = tid & 63, wid = tid >> 6;
  int b = blockIdx.x / (NN / 4);
  int n = (blockIdx.x % (NN / 4)) * 4 + wid;
  for (int t = tid; t < NM; t += 256) {
    float x = v_pos[((size_t)b * NM + t) * 3 + 0];
    float y = v_pos[((size_t)b * NM + t) * 3 + 1];
    float z = v_pos[((size_t)b * NM + t) * 3 + 2];
    cpos[t] = make_float4(x, y, z, x * x + y * y + z * z);
  }
  __syncthreads();
  float qx = q_pos[((size_t)b * NN + n) * 3 + 0];
  float qy = q_pos[((size_t)b * NN + n) * 3 + 1];
  float qz = q_pos[((size_t)b * NN + n) * 3 + 2];
  float qq = qx * qx + qy * qy + qz * qz;
  float bd[NK];
  int bi[NK];
#pragma unroll
  for (int j = 0; j < NK; ++j) { bd[j] = 1e30f; bi[j] = 0x7fffffff; }
#pragma unroll
  for (int t = 0; t < NM / 64; ++t) {
    int m = t * 64 + lane;
    float4 cc = cpos[m];
    float d = qq + cc.w - 2.f * (qx * cc.x + qy * cc.y + qz * cc.z);
    if (d < bd[NK - 1]) {
#pragma unroll
      for (int j = NK - 1; j > 0; --j) {
        if (d < bd[j - 1]) { bd[j] = bd[j - 1]; bi[j] = bi[j - 1]; }
        else if (d < bd[j]) { bd[j] = d; bi[j] = m; }
      }
      if (d < bd[0]) { bd[0] = d; bi[0] = m; }
    }
  }
  size_t base = ((size_t)b * NN + n) * NK;
#pragma unroll
  for (int round = 0; round < NK; ++round) {
    float dh = bd[0];
    int mh = bi[0];
    wred_argmin(dh, mh);
    if (lane == 0) knn_idx[base + round] = mh;
    if (bi[0] == mh) {
#pragma unroll
      for (int j = 0; j < NK - 1; ++j) { bd[j] = bd[j + 1]; bi[j] = bi[j + 1]; }
      bd[NK - 1] = 1e30f; bi[NK - 1] = 0x7fffffff;
    }
  }
}

// fused MLP + three_nn: one wave per (b,g,n,k) row
__global__ __launch_bounds__(256) void mlp3nn_k(
    const float* __restrict__ vcontrib, const float* __restrict__ qcontrib,
    const float* __restrict__ boff1, const float* __restrict__ ln_g,
    const float* __restrict__ ln_b, const float* __restrict__ Woff2,
    const int* __restrict__ knn_idx, const float* __restrict__ v_pos,
    int* __restrict__ idx3, float* __restrict__ w3) {
  __shared__ float4 cpos[NM];
  int tid = threadIdx.x, lane = tid & 63, wid = tid >> 6;
  int r = blockIdx.x * 4 + wid;
  int b = (blockIdx.x * 4) / (NK * NN * NG);
  for (int t = tid; t < NM; t += 256) {
    float x = v_pos[((size_t)b * NM + t) * 3 + 0];
    float y = v_pos[((size_t)b * NM + t) * 3 + 1];
    float z = v_pos[((size_t)b * NM + t) * 3 + 2];
    cpos[t] = make_float4(x, y, z, x * x + y * y + z * z);
  }
  __syncthreads();
  int k = r % NK;
  int n = (r / NK) % NN;
  int g = (r / (NK * NN)) % NG;
  int m = knn_idx[((size_t)b * NN + n) * NK + k];
  const float* vc = vcontrib + ((size_t)(g * NB + b) * NM + m) * NC;
  const float* qc = qcontrib + ((size_t)(g * NB + b) * NN + n) * NC;
  float h[6];
  float s = 0.f, s2 = 0.f;
#pragma unroll
  for (int j = 0; j < 6; ++j) {
    int c = j * 64 + lane;
    float x = vc[c] + qc[c] + boff1[c];
    h[j] = x; s += x; s2 += x * x;
  }
  s = wred_sum(s);
  s2 = wred_sum(s2);
  float mean = s * (1.f / NC);
  float var = s2 * (1.f / NC) - mean * mean;
  float inv = 1.f / sqrtf(var + 1e-5f);
  float p0 = 0.f, p1 = 0.f, p2 = 0.f;
#pragma unroll
  for (int j = 0; j < 6; ++j) {
    int c = j * 64 + lane;
    float x = (h[j] - mean) * inv * ln_g[c] + ln_b[c];
    x = 0.5f * x * (1.f + erff(x * 0.70710678118654752f));
    p0 = fmaf(x, Woff2[0 * NC + c], p0);
    p1 = fmaf(x, Woff2[1 * NC + c], p1);
    p2 = fmaf(x, Woff2[2 * NC + c], p2);
  }
  p0 = wred_sum(p0);
  p1 = wred_sum(p1);
  p2 = wred_sum(p2);
  float4 cm = cpos[m];
  float sx = cm.x + tanhf(p0);
  float sy = cm.y + tanhf(p1);
  float sz = cm.z + tanhf(p2);
  float qq2 = sx * sx + sy * sy + sz * sz;
  float d0v = 1e30f, d1v = 1e30f, d2v = 1e30f;
  int i0v = 0x7fffffff, i1v = 0x7fffffff, i2v = 0x7fffffff;
#pragma unroll
  for (int t = 0; t < NM / 64; ++t) {
    int m2 = t * 64 + lane;
    float4 cc = cpos[m2];
    float d = qq2 + cc.w - 2.f * (sx * cc.x + sy * cc.y + sz * cc.z);
    if (d < d2v) {
      d2v = d; i2v = m2;
      if (d2v < d1v) { float td = d1v; d1v = d2v; d2v = td; int ti = i1v; i1v = i2v; i2v = ti; }
      if (d1v < d0v) { float td = d0v; d0v = d1v; d1v = td; int ti = i0v; i0v = i1v; i1v = ti; }
    }
  }
  float rd[3];
  int rm[3];
#pragma unroll
  for (int round = 0; round < 3; ++round) {
    float dh = d0v;
    int mh = i0v;
    wred_argmin(dh, mh);
    rd[round] = dh; rm[round] = mh;
    if (i0v == mh) {
      d0v = d1v; i0v = i1v;
      d1v = d2v; i1v = i2v;
      d2v = 1e30f; i2v = 0x7fffffff;
    }
  }
  if (lane == 0) {
    float e0 = 1.f / (sqrtf(fmaxf(rd[0], 0.f)) + 1e-8f);
    float e1 = 1.f / (sqrtf(fmaxf(rd[1], 0.f)) + 1e-8f);
    float e2 = 1.f / (sqrtf(fmaxf(rd[2], 0.f)) + 1e-8f);
    float sw = e0 + e1 + e2;
    idx3[(size_t)r * 3 + 0] = rm[0]; w3[(size_t)r * 3 + 0] = e0 / sw;
    idx3[(size_t)r * 3 + 1] = rm[1]; w3[(size_t)r * 3 + 1] = e1 / sw;
    idx3[(size_t)r * 3 + 2] = rm[2]; w3[(size_t)r * 3 + 2] = e2 / sw;
  }
}

// one block per (b,n): gathered kf/vf (bf16 tables), vf kept in registers,
// ONE merged 6-step butterfly for all 10 logits, softmax in registers.
__global__ __launch_bounds__(NC) void attn_k(const float* __restrict__ qp,
                                             const ushort* __restrict__ Kc,
                                             const ushort* __restrict__ Vc,
                                             const int* __restrict__ idx3,
                                             const float* __restrict__ w3,
                                             float* __restrict__ attn_out) {
  __shared__ int il[NG][NK][3];
  __shared__ float wl[NG][NK][3];
  int o = threadIdx.x;
  int b = blockIdx.x / NN;
  int n = blockIdx.x % NN;
  if (o < NG * NK * 3) {
    int g = o / (NK * 3), k = (o / 3) % NK, j = o % 3;
    size_t rr = (((size_t)(b * NG + g) * NN + n) * NK + k) * 3 + j;
    il[g][k][j] = idx3[rr];
    wl[g][k][j] = w3[rr];
  }
  __syncthreads();
  float qv = qp[((size_t)b * NN + n) * NC + o];
  float p[NK], vf[NK];
#pragma unroll
  for (int k = 0; k < NK; ++k) {
    float kf = 0.f, v_ = 0.f;
#pragma unroll
    for (int g = 0; g < NG; ++g)
#pragma unroll
      for (int j = 0; j < 3; ++j) {
        int m = il[g][k][j];
        float w = wl[g][k][j];
        size_t base = ((size_t)(g * NB + b) * NM + m) * NC + o;
        kf = fmaf(w, b2f(Kc[base]), kf);
        v_ = fmaf(w, b2f(Vc[base]), v_);
      }
    vf[k] = v_;
    p[k] = qv * kf;
  }
  // merged butterfly: 10 independent reductions, pipelined per step
#pragma unroll
  for (int off = 32; off >= 1; off >>= 1) {
#pragma unroll
    for (int k = 0; k < NK; ++k) p[k] += __shfl_xor(p[k], off, 64);
  }
  float a[NK];
  float mx = -1e30f;
#pragma unroll
  for (int k = 0; k < NK; ++k) { a[k] = p[k] * 0.125f; mx = fmaxf(mx, a[k]); }
  float sum = 0.f;
#pragma unroll
  for (int k = 0; k < NK; ++k) { a[k] = expf(a[k] - mx); sum += a[k]; }
  float outv = 0.f;
#pragma unroll
  for (int k = 0; k < NK; ++k) outv = fmaf(a[k] / sum, vf[k], outv);
  attn_out[((size_t)b * NN + n) * NC + o] = outv;
}

extern "C" void kernel_launch(void* const* d_in, const int* in_sizes, int n_in,
                              void* d_out, int out_size, void* d_ws, size_t ws_size,
                              hipStream_t stream) {
  (void)in_sizes; (void)n_in; (void)out_size; (void)ws_size;
  const float* q     = (const float*)d_in[0];
  const float* q_pos = (const float*)d_in[1];
  const float* v     = (const float*)d_in[2];
  const float* v_pos = (const float*)d_in[3];
  const float* Wq    = (const float*)d_in[4];
  const float* Wk    = (const float*)d_in[5];
  const float* Wv    = (const float*)d_in[6];
  const float* Wvoff = (const float*)d_in[7];
  const float* Woff1 = (const float*)d_in[8];
  const float* boff1 = (const float*)d_in[9];
  const float* ln_g  = (const float*)d_in[10];
  const float* ln_b  = (const float*)d_in[11];
  const float* Woff2 = (const float*)d_in[12];
  const float* Wproj = (const float*)d_in[13];
  const float* bproj = (const float*)d_in[14];
  float* out = (float*)d_out;

  char* p = (char*)d_ws;
  auto alloc_f = [&](size_t n) { float* r = (float*)p; p += n * sizeof(float); return r; };
  auto alloc_h = [&](size_t n) { ushort* r = (ushort*)p; p += n * sizeof(ushort); return r; };
  auto alloc_i = [&](size_t n) { int* r = (int*)p; p += n * sizeof(int); return r; };

  float* qp        = alloc_f(QSZ);
  float* qcontrib  = alloc_f((size_t)NG * QSZ);
  float* vcontrib  = alloc_f((size_t)NG * GSZ);
  float* Wt_all    = alloc_f((size_t)WT_ALL_FLOATS);
  float* Wcomb_t   = alloc_f((size_t)NG * NCNC);
  float* w3        = alloc_f((size_t)NB * NG * NN * NK * 3);
  ushort* KcT      = alloc_h((size_t)NG * GSZ);
  ushort* VcT      = alloc_h((size_t)NG * GSZ);
  int* knn_idx     = alloc_i((size_t)NB * NN * NK);
  int* idx3        = alloc_i((size_t)NB * NG * NN * NK * 3);
  float* attn_out  = vcontrib;  // vcontrib dead after mlp3nn_k; reuse

  transpose_all_k<<<dim3(576, 7), 256, 0, stream>>>(Wq, Woff1, Wk, Wv, Wproj, Wt_all);
  wcomb_k<<<dim3(NC, NG), NC, 0, stream>>>(Woff1, Wvoff, Wcomb_t);

  gemm16_k<<<dim3(NB * NN / 16, 1), 384, 0, stream>>>(q, NC, 0, 0, Wt_all + OFF_WQ, 0, nullptr,
                                                      qp, 0);
  knn2_k<<<NB * (NN / 4), 256, 0, stream>>>(q_pos, v_pos, knn_idx);
  gemm16_k<<<dim3(NB * NN / 16, 2), 384, 0, stream>>>(qp, NGC, 0, NGC, Wt_all + OFF_W1B, 0,
                                                      nullptr, qcontrib, QSZ);
  vproj_k<<<dim3(NB * NM / 16, 6), 384, 0, stream>>>(v, Wcomb_t, Wt_all, vcontrib, KcT, VcT);

  mlp3nn_k<<<NB * NG * NN * NK / 4, 256, 0, stream>>>(vcontrib, qcontrib, boff1, ln_g, ln_b,
                                                      Woff2, knn_idx, v_pos, idx3, w3);
  attn_k<<<NB * NN, NC, 0, stream>>>(qp, KcT, VcT, idx3, w3, attn_out);
  gemm16_k<<<dim3(NB * NN / 16, 1), 384, 0, stream>>>(attn_out, NC, 0, 0, Wt_all + OFF_WPROJ, 0,
                                                      bproj, out, 0);
}

// Round 9
// 476.948 us; speedup vs baseline: 1.1128x; 1.1128x over previous
//
#include <hip/hip_runtime.h>
#include <math.h>

#define NB 4
#define NN 1024
#define NM 1024
#define NC 384
#define NK 10
#define NG 2
#define NGC 192
#define NH 6

#define GSZ ((size_t)NB * NM * NC)   // per-g table size (elements)
#define QSZ ((size_t)NB * NN * NC)
#define NCNC ((size_t)NC * NC)

// Wt_all layout (floats)
#define OFF_WQ 0
#define OFF_W1B 147456
#define OFF_WK0 221184
#define OFF_WK1 294912
#define OFF_WV0 368640
#define OFF_WV1 442368
#define OFF_WPROJ 516096
#define WT_ALL_FLOATS 663552

__device__ __forceinline__ float wred_sum(float v) {
#pragma unroll
  for (int m = 32; m >= 1; m >>= 1) v += __shfl_xor(v, m, 64);
  return v;
}

__device__ __forceinline__ ushort f2bf(float x) {  // RNE, finite inputs
  unsigned u = __float_as_uint(x);
  unsigned r = (u + 0x7fffu + ((u >> 16) & 1u)) >> 16;
  return (ushort)r;
}
__device__ __forceinline__ float b2f(ushort s) {
  return __uint_as_float(((unsigned)s) << 16);
}

// all 7 weight transposes in one launch; blockIdx.y = job
__global__ void transpose_all_k(const float* __restrict__ Wq, const float* __restrict__ Woff1,
                                const float* __restrict__ Wk, const float* __restrict__ Wv,
                                const float* __restrict__ Wproj, float* __restrict__ Wt_all) {
  const float* W;
  int i0, icount, doff;
  switch (blockIdx.y) {
    case 0: W = Wq;    i0 = 0;   icount = NC;  doff = OFF_WQ;    break;
    case 1: W = Woff1; i0 = NGC; icount = NGC; doff = OFF_W1B;   break;
    case 2: W = Wk;    i0 = 0;   icount = NGC; doff = OFF_WK0;   break;
    case 3: W = Wk;    i0 = NGC; icount = NGC; doff = OFF_WK1;   break;
    case 4: W = Wv;    i0 = 0;   icount = NGC; doff = OFF_WV0;   break;
    case 5: W = Wv;    i0 = NGC; icount = NGC; doff = OFF_WV1;   break;
    default: W = Wproj; i0 = 0;  icount = NC;  doff = OFF_WPROJ; break;
  }
  int id = blockIdx.x * 256 + threadIdx.x;
  if (id >= icount * NC) return;
  int o = id % NC;
  int i = id / NC;
  Wt_all[doff + (size_t)i * NC + o] = W[(size_t)o * NC + i0 + i];
}

// Wcomb_t[g][i][o] = sum_j Woff1[o][j] * Wvoff[g*192+j][i]   (j < 192)
__global__ void wcomb_k(const float* __restrict__ Woff1, const float* __restrict__ Wvoff,
                        float* __restrict__ Wcomb_t) {
  int o = blockIdx.x;
  int g = blockIdx.y;
  int i = threadIdx.x;
  __shared__ float w1[NGC];
  if (i < NGC) w1[i] = Woff1[(size_t)o * NC + i];
  __syncthreads();
  float acc = 0.f;
#pragma unroll 4
  for (int j = 0; j < NGC; ++j)
    acc = fmaf(w1[j], Wvoff[(size_t)(g * NGC + j) * NC + i], acc);
  Wcomb_t[((size_t)g * NC + i) * NC + o] = acc;
}

// generic 16-row 4x4 register-blocked GEMM; blockIdx.y = job
__global__ __launch_bounds__(384) void gemm16_k(const float* __restrict__ X, int IN, int xoff0,
                                                int xoff_stride, const float* __restrict__ Wt0,
                                                size_t wstride, const float* __restrict__ bias,
                                                float* __restrict__ Y0, size_t ystride) {
  __shared__ __align__(16) float xs[NC][20];
  int tid = threadIdx.x;
  int og = tid % 96, rg = tid / 96;
  int r0 = blockIdx.x * 16;
  int job = blockIdx.y;
  int xoff = xoff0 + job * xoff_stride;
  const float* Wt = Wt0 + (size_t)job * wstride;
  float* Y = Y0 + (size_t)job * ystride;
  for (int t = tid; t < 16 * IN; t += 384) {
    int r = t / IN, kk = t % IN;
    xs[kk][r] = X[(size_t)(r0 + r) * NC + xoff + kk];
  }
  __syncthreads();
  float acc[4][4];
#pragma unroll
  for (int i = 0; i < 4; ++i)
#pragma unroll
    for (int j = 0; j < 4; ++j) acc[i][j] = 0.f;
  int o = og * 4;
#pragma unroll 4
  for (int kk = 0; kk < IN; ++kk) {
    float4 w4 = *(const float4*)&Wt[(size_t)kk * NC + o];
    float4 x4 = *(const float4*)&xs[kk][rg * 4];
    float xr[4] = {x4.x, x4.y, x4.z, x4.w};
    float wr[4] = {w4.x, w4.y, w4.z, w4.w};
#pragma unroll
    for (int ri = 0; ri < 4; ++ri)
#pragma unroll
      for (int oi = 0; oi < 4; ++oi) acc[ri][oi] = fmaf(xr[ri], wr[oi], acc[ri][oi]);
  }
  float4 bv = make_float4(0.f, 0.f, 0.f, 0.f);
  if (bias) bv = *(const float4*)&bias[o];
#pragma unroll
  for (int ri = 0; ri < 4; ++ri) {
    float4 ov;
    ov.x = acc[ri][0] + bv.x;
    ov.y = acc[ri][1] + bv.y;
    ov.z = acc[ri][2] + bv.z;
    ov.w = acc[ri][3] + bv.w;
    *(float4*)&Y[(size_t)(r0 + rg * 4 + ri) * NC + o] = ov;
  }
}

// v projections, blockIdx.y = job; jobs 2-5 write bf16
__global__ __launch_bounds__(384) void vproj_k(const float* __restrict__ v,
                                               const float* __restrict__ Wcomb_t,
                                               const float* __restrict__ Wt_all,
                                               float* __restrict__ vcontrib,
                                               ushort* __restrict__ KcT,
                                               ushort* __restrict__ VcT) {
  __shared__ __align__(16) float xs[NC][20];
  int tid = threadIdx.x;
  int og = tid % 96, rg = tid / 96;
  int r0 = blockIdx.x * 16;
  int job = blockIdx.y;
  const float* Wt;
  float* Yf = nullptr;
  ushort* Yh = nullptr;
  int IN, xoff;
  switch (job) {
    case 0: Wt = Wcomb_t;        IN = NC;  xoff = 0;   Yf = vcontrib;       break;
    case 1: Wt = Wcomb_t + NCNC; IN = NC;  xoff = 0;   Yf = vcontrib + GSZ; break;
    case 2: Wt = Wt_all + OFF_WK0; IN = NGC; xoff = 0;   Yh = KcT;          break;
    case 3: Wt = Wt_all + OFF_WK1; IN = NGC; xoff = NGC; Yh = KcT + GSZ;    break;
    case 4: Wt = Wt_all + OFF_WV0; IN = NGC; xoff = 0;   Yh = VcT;          break;
    default: Wt = Wt_all + OFF_WV1; IN = NGC; xoff = NGC; Yh = VcT + GSZ;   break;
  }
  for (int t = tid; t < 16 * IN; t += 384) {
    int r = t / IN, kk = t % IN;
    xs[kk][r] = v[(size_t)(r0 + r) * NC + xoff + kk];
  }
  __syncthreads();
  float acc[4][4];
#pragma unroll
  for (int i = 0; i < 4; ++i)
#pragma unroll
    for (int j = 0; j < 4; ++j) acc[i][j] = 0.f;
  int o = og * 4;
#pragma unroll 4
  for (int kk = 0; kk < IN; ++kk) {
    float4 w4 = *(const float4*)&Wt[(size_t)kk * NC + o];
    float4 x4 = *(const float4*)&xs[kk][rg * 4];
    float xr[4] = {x4.x, x4.y, x4.z, x4.w};
    float wr[4] = {w4.x, w4.y, w4.z, w4.w};
#pragma unroll
    for (int ri = 0; ri < 4; ++ri)
#pragma unroll
      for (int oi = 0; oi < 4; ++oi) acc[ri][oi] = fmaf(xr[ri], wr[oi], acc[ri][oi]);
  }
  if (Yf) {
#pragma unroll
    for (int ri = 0; ri < 4; ++ri)
      *(float4*)&Yf[(size_t)(r0 + rg * 4 + ri) * NC + o] =
          make_float4(acc[ri][0], acc[ri][1], acc[ri][2], acc[ri][3]);
  } else {
#pragma unroll
    for (int ri = 0; ri < 4; ++ri) {
      ushort4 pk;
      pk.x = f2bf(acc[ri][0]);
      pk.y = f2bf(acc[ri][1]);
      pk.z = f2bf(acc[ri][2]);
      pk.w = f2bf(acc[ri][3]);
      *(ushort4*)&Yh[(size_t)(r0 + rg * 4 + ri) * NC + o] = pk;
    }
  }
}

// wave-per-query KNN: lane scans 16 candidates -> register top-10 -> argmin-merge
__global__ __launch_bounds__(256) void knn2_k(const float* __restrict__ q_pos,
                                              const float* __restrict__ v_pos,
                                              int* __restrict__ knn_idx) {
  __shared__ float4 cpos[NM];
  int tid = threadIdx.x, lane = tid & 63, wid = tid >> 6;
  int b = blockIdx.x / (NN / 4);
  int n = (blockIdx.x % (NN / 4)) * 4 + wid;
  for (int t = tid; t < NM; t += 256) {
    float x = v_pos[((size_t)b * NM + t) * 3 + 0];
    float y = v_pos[((size_t)b * NM + t) * 3 + 1];
    float z = v_pos[((size_t)b * NM + t) * 3 + 2];
    cpos[t] = make_float4(x, y, z, x * x + y * y + z * z);
  }
  __syncthreads();
  float qx = q_pos[((size_t)b * NN + n) * 3 + 0];
  float qy = q_pos[((size_t)b * NN + n) * 3 + 1];
  float qz = q_pos[((size_t)b * NN + n) * 3 + 2];
  float qq = qx * qx + qy * qy + qz * qz;
  float bd[NK];
  int bi[NK];
#pragma unroll
  for (int j = 0; j < NK; ++j) { bd[j] = 1e30f; bi[j] = 0x7fffffff; }
#pragma unroll
  for (int t = 0; t < NM / 64; ++t) {
    int m = t * 64 + lane;
    float4 cc = cpos[m];
    float d = qq + cc.w - 2.f * (qx * cc.x + qy * cc.y + qz * cc.z);
    if (d < bd[NK - 1]) {
#pragma unroll
      for (int j = NK - 1; j > 0; --j) {
        if (d < bd[j - 1]) { bd[j] = bd[j - 1]; bi[j] = bi[j - 1]; }
        else if (d < bd[j]) { bd[j] = d; bi[j] = m; }
      }
      if (d < bd[0]) { bd[0] = d; bi[0] = m; }
    }
  }
  size_t base = ((size_t)b * NN + n) * NK;
#pragma unroll
  for (int round = 0; round < NK; ++round) {
    float dh = bd[0];
    int mh = bi[0];
#pragma unroll
    for (int off = 32; off >= 1; off >>= 1) {
      float od = __shfl_xor(dh, off, 64);
      int om = __shfl_xor(mh, off, 64);
      if (od < dh || (od == dh && om < mh)) { dh = od; mh = om; }
    }
    if (lane == 0) knn_idx[base + round] = mh;
    if (bi[0] == mh) {
#pragma unroll
      for (int j = 0; j < NK - 1; ++j) { bd[j] = bd[j + 1]; bi[j] = bi[j + 1]; }
      bd[NK - 1] = 1e30f; bi[NK - 1] = 0x7fffffff;
    }
  }
}

// fused MLP + three_nn: one wave per TWO (b,g,n,k) rows; branchless top-3 insert;
// all butterfly chains 2-row interleaved for latency hiding.
__global__ __launch_bounds__(256) void mlp3nn_k(
    const float* __restrict__ vcontrib, const float* __restrict__ qcontrib,
    const float* __restrict__ boff1, const float* __restrict__ ln_g,
    const float* __restrict__ ln_b, const float* __restrict__ Woff2,
    const int* __restrict__ knn_idx, const float* __restrict__ v_pos,
    int* __restrict__ idx3, float* __restrict__ w3) {
  __shared__ float4 cpos[NM];
  int tid = threadIdx.x, lane = tid & 63, wid = tid >> 6;
  int ra = blockIdx.x * 8 + wid * 2;
  int rb = ra + 1;
  int b = (blockIdx.x * 8) / (NK * NN * NG);  // uniform per block (20480 % 8 == 0)
  for (int t = tid; t < NM; t += 256) {
    float x = v_pos[((size_t)b * NM + t) * 3 + 0];
    float y = v_pos[((size_t)b * NM + t) * 3 + 1];
    float z = v_pos[((size_t)b * NM + t) * 3 + 2];
    cpos[t] = make_float4(x, y, z, x * x + y * y + z * z);
  }
  __syncthreads();
  int ka = ra % NK, na = (ra / NK) % NN, ga = (ra / (NK * NN)) % NG;
  int kb = rb % NK, nb = (rb / NK) % NN, gb = (rb / (NK * NN)) % NG;
  int ma = knn_idx[((size_t)b * NN + na) * NK + ka];
  int mb = knn_idx[((size_t)b * NN + nb) * NK + kb];
  const float* vca = vcontrib + ((size_t)(ga * NB + b) * NM + ma) * NC;
  const float* qca = qcontrib + ((size_t)(ga * NB + b) * NN + na) * NC;
  const float* vcb = vcontrib + ((size_t)(gb * NB + b) * NM + mb) * NC;
  const float* qcb = qcontrib + ((size_t)(gb * NB + b) * NN + nb) * NC;
  float ha[6], hb[6];
  float sa = 0.f, s2a = 0.f, sb = 0.f, s2b = 0.f;
#pragma unroll
  for (int j = 0; j < 6; ++j) {
    int c = j * 64 + lane;
    float bo = boff1[c];
    float xa = vca[c] + qca[c] + bo;
    float xb = vcb[c] + qcb[c] + bo;
    ha[j] = xa; sa += xa; s2a += xa * xa;
    hb[j] = xb; sb += xb; s2b += xb * xb;
  }
#pragma unroll
  for (int off = 32; off >= 1; off >>= 1) {
    sa += __shfl_xor(sa, off, 64);
    s2a += __shfl_xor(s2a, off, 64);
    sb += __shfl_xor(sb, off, 64);
    s2b += __shfl_xor(s2b, off, 64);
  }
  float meana = sa * (1.f / NC), meanb = sb * (1.f / NC);
  float vara = s2a * (1.f / NC) - meana * meana;
  float varb = s2b * (1.f / NC) - meanb * meanb;
  float inva = 1.f / sqrtf(vara + 1e-5f);
  float invb = 1.f / sqrtf(varb + 1e-5f);
  float p0a = 0.f, p1a = 0.f, p2a = 0.f, p0b = 0.f, p1b = 0.f, p2b = 0.f;
#pragma unroll
  for (int j = 0; j < 6; ++j) {
    int c = j * 64 + lane;
    float gg = ln_g[c], bb = ln_b[c];
    float w0 = Woff2[0 * NC + c], w1 = Woff2[1 * NC + c], w2 = Woff2[2 * NC + c];
    float xa = (ha[j] - meana) * inva * gg + bb;
    xa = 0.5f * xa * (1.f + erff(xa * 0.70710678118654752f));
    float xb = (hb[j] - meanb) * invb * gg + bb;
    xb = 0.5f * xb * (1.f + erff(xb * 0.70710678118654752f));
    p0a = fmaf(xa, w0, p0a); p1a = fmaf(xa, w1, p1a); p2a = fmaf(xa, w2, p2a);
    p0b = fmaf(xb, w0, p0b); p1b = fmaf(xb, w1, p1b); p2b = fmaf(xb, w2, p2b);
  }
#pragma unroll
  for (int off = 32; off >= 1; off >>= 1) {
    p0a += __shfl_xor(p0a, off, 64);
    p1a += __shfl_xor(p1a, off, 64);
    p2a += __shfl_xor(p2a, off, 64);
    p0b += __shfl_xor(p0b, off, 64);
    p1b += __shfl_xor(p1b, off, 64);
    p2b += __shfl_xor(p2b, off, 64);
  }
  float4 cma = cpos[ma], cmb = cpos[mb];
  float sxa = cma.x + tanhf(p0a), sya = cma.y + tanhf(p1a), sza = cma.z + tanhf(p2a);
  float sxb = cmb.x + tanhf(p0b), syb = cmb.y + tanhf(p1b), szb = cmb.z + tanhf(p2b);
  float qqa = sxa * sxa + sya * sya + sza * sza;
  float qqb = sxb * sxb + syb * syb + szb * szb;
  float d0a = 1e30f, d1a = 1e30f, d2a = 1e30f;
  float d0b = 1e30f, d1b = 1e30f, d2b = 1e30f;
  int i0a = 0x7fffffff, i1a = 0x7fffffff, i2a = 0x7fffffff;
  int i0b = 0x7fffffff, i1b = 0x7fffffff, i2b = 0x7fffffff;
#pragma unroll 4
  for (int t = 0; t < NM / 64; ++t) {
    int m2 = t * 64 + lane;
    float4 cc = cpos[m2];
    float da = qqa + cc.w - 2.f * (sxa * cc.x + sya * cc.y + sza * cc.z);
    float db = qqb + cc.w - 2.f * (sxb * cc.x + syb * cc.y + szb * cc.z);
    // branchless sorted-3 insert; strict < (equal d keeps earlier index).
    // update order matters: i2/d2 use OLD d1/i1; i1/d1 use OLD d0/i0.
    i2a = (da < d1a) ? i1a : ((da < d2a) ? m2 : i2a);
    d2a = fminf(fmaxf(da, d1a), d2a);
    i1a = (da < d0a) ? i0a : ((da < d1a) ? m2 : i1a);
    d1a = fminf(fmaxf(da, d0a), d1a);
    i0a = (da < d0a) ? m2 : i0a;
    d0a = fminf(da, d0a);
    i2b = (db < d1b) ? i1b : ((db < d2b) ? m2 : i2b);
    d2b = fminf(fmaxf(db, d1b), d2b);
    i1b = (db < d0b) ? i0b : ((db < d1b) ? m2 : i1b);
    d1b = fminf(fmaxf(db, d0b), d1b);
    i0b = (db < d0b) ? m2 : i0b;
    d0b = fminf(db, d0b);
  }
  float rda[3], rdb[3];
  int rma[3], rmb[3];
#pragma unroll
  for (int round = 0; round < 3; ++round) {
    float dha = d0a; int mha = i0a;
    float dhb = d0b; int mhb = i0b;
#pragma unroll
    for (int off = 32; off >= 1; off >>= 1) {
      float oda = __shfl_xor(dha, off, 64); int oma = __shfl_xor(mha, off, 64);
      float odb = __shfl_xor(dhb, off, 64); int omb = __shfl_xor(mhb, off, 64);
      if (oda < dha || (oda == dha && oma < mha)) { dha = oda; mha = oma; }
      if (odb < dhb || (odb == dhb && omb < mhb)) { dhb = odb; mhb = omb; }
    }
    rda[round] = dha; rma[round] = mha;
    rdb[round] = dhb; rmb[round] = mhb;
    if (i0a == mha) { d0a = d1a; i0a = i1a; d1a = d2a; i1a = i2a; d2a = 1e30f; i2a = 0x7fffffff; }
    if (i0b == mhb) { d0b = d1b; i0b = i1b; d1b = d2b; i1b = i2b; d2b = 1e30f; i2b = 0x7fffffff; }
  }
  if (lane == 0) {
    float e0 = 1.f / (sqrtf(fmaxf(rda[0], 0.f)) + 1e-8f);
    float e1 = 1.f / (sqrtf(fmaxf(rda[1], 0.f)) + 1e-8f);
    float e2 = 1.f / (sqrtf(fmaxf(rda[2], 0.f)) + 1e-8f);
    float sw = e0 + e1 + e2;
    idx3[(size_t)ra * 3 + 0] = rma[0]; w3[(size_t)ra * 3 + 0] = e0 / sw;
    idx3[(size_t)ra * 3 + 1] = rma[1]; w3[(size_t)ra * 3 + 1] = e1 / sw;
    idx3[(size_t)ra * 3 + 2] = rma[2]; w3[(size_t)ra * 3 + 2] = e2 / sw;
    float f0 = 1.f / (sqrtf(fmaxf(rdb[0], 0.f)) + 1e-8f);
    float f1 = 1.f / (sqrtf(fmaxf(rdb[1], 0.f)) + 1e-8f);
    float f2 = 1.f / (sqrtf(fmaxf(rdb[2], 0.f)) + 1e-8f);
    float sw2 = f0 + f1 + f2;
    idx3[(size_t)rb * 3 + 0] = rmb[0]; w3[(size_t)rb * 3 + 0] = f0 / sw2;
    idx3[(size_t)rb * 3 + 1] = rmb[1]; w3[(size_t)rb * 3 + 1] = f1 / sw2;
    idx3[(size_t)rb * 3 + 2] = rmb[2]; w3[(size_t)rb * 3 + 2] = f2 / sw2;
  }
}

// one block per (b,n): serial per-k gathered kf/vf (bf16 tables) with LDS vfs —
// small register footprint; TLP (24k waves) hides gather latency.
__global__ __launch_bounds__(NC) void attn_k(const float* __restrict__ qp,
                                             const ushort* __restrict__ Kc,
                                             const ushort* __restrict__ Vc,
                                             const int* __restrict__ idx3,
                                             const float* __restrict__ w3,
                                             float* __restrict__ attn_out) {
  __shared__ float vfs[NK][NC];
  __shared__ float lgs[NH][NK];
  __shared__ int il[NG][NK][3];
  __shared__ float wl[NG][NK][3];
  int o = threadIdx.x;
  int lane = o & 63, wid = o >> 6;
  int b = blockIdx.x / NN;
  int n = blockIdx.x % NN;
  if (o < NG * NK * 3) {
    int g = o / (NK * 3), k = (o / 3) % NK, j = o % 3;
    size_t rr = (((size_t)(b * NG + g) * NN + n) * NK + k) * 3 + j;
    il[g][k][j] = idx3[rr];
    wl[g][k][j] = w3[rr];
  }
  __syncthreads();
  float qv = qp[((size_t)b * NN + n) * NC + o];
  for (int k = 0; k < NK; ++k) {
    float kf = 0.f, vf = 0.f;
#pragma unroll
    for (int g = 0; g < NG; ++g)
#pragma unroll
      for (int j = 0; j < 3; ++j) {
        int m = il[g][k][j];
        float w = wl[g][k][j];
        size_t base = ((size_t)(g * NB + b) * NM + m) * NC + o;
        kf = fmaf(w, b2f(Kc[base]), kf);
        vf = fmaf(w, b2f(Vc[base]), vf);
      }
    vfs[k][o] = vf;
    float p = wred_sum(qv * kf);
    if (lane == 0) lgs[wid][k] = p * 0.125f;
  }
  __syncthreads();
  float a[NK];
  float mx = -1e30f;
#pragma unroll
  for (int k = 0; k < NK; ++k) { a[k] = lgs[wid][k]; mx = fmaxf(mx, a[k]); }
  float sum = 0.f;
#pragma unroll
  for (int k = 0; k < NK; ++k) { a[k] = expf(a[k] - mx); sum += a[k]; }
  float outv = 0.f;
#pragma unroll
  for (int k = 0; k < NK; ++k) outv = fmaf(a[k] / sum, vfs[k][o], outv);
  attn_out[((size_t)b * NN + n) * NC + o] = outv;
}

extern "C" void kernel_launch(void* const* d_in, const int* in_sizes, int n_in,
                              void* d_out, int out_size, void* d_ws, size_t ws_size,
                              hipStream_t stream) {
  (void)in_sizes; (void)n_in; (void)out_size; (void)ws_size;
  const float* q     = (const float*)d_in[0];
  const float* q_pos = (const float*)d_in[1];
  const float* v     = (const float*)d_in[2];
  const float* v_pos = (const float*)d_in[3];
  const float* Wq    = (const float*)d_in[4];
  const float* Wk    = (const float*)d_in[5];
  const float* Wv    = (const float*)d_in[6];
  const float* Wvoff = (const float*)d_in[7];
  const float* Woff1 = (const float*)d_in[8];
  const float* boff1 = (const float*)d_in[9];
  const float* ln_g  = (const float*)d_in[10];
  const float* ln_b  = (const float*)d_in[11];
  const float* Woff2 = (const float*)d_in[12];
  const float* Wproj = (const float*)d_in[13];
  const float* bproj = (const float*)d_in[14];
  float* out = (float*)d_out;

  char* p = (char*)d_ws;
  auto alloc_f = [&](size_t n) { float* r = (float*)p; p += n * sizeof(float); return r; };
  auto alloc_h = [&](size_t n) { ushort* r = (ushort*)p; p += n * sizeof(ushort); return r; };
  auto alloc_i = [&](size_t n) { int* r = (int*)p; p += n * sizeof(int); return r; };

  float* qp        = alloc_f(QSZ);
  float* qcontrib  = alloc_f((size_t)NG * QSZ);
  float* vcontrib  = alloc_f((size_t)NG * GSZ);
  float* Wt_all    = alloc_f((size_t)WT_ALL_FLOATS);
  float* Wcomb_t   = alloc_f((size_t)NG * NCNC);
  float* w3        = alloc_f((size_t)NB * NG * NN * NK * 3);
  ushort* KcT      = alloc_h((size_t)NG * GSZ);
  ushort* VcT      = alloc_h((size_t)NG * GSZ);
  int* knn_idx     = alloc_i((size_t)NB * NN * NK);
  int* idx3        = alloc_i((size_t)NB * NG * NN * NK * 3);
  float* attn_out  = vcontrib;  // vcontrib dead after mlp3nn_k; reuse

  transpose_all_k<<<dim3(576, 7), 256, 0, stream>>>(Wq, Woff1, Wk, Wv, Wproj, Wt_all);
  wcomb_k<<<dim3(NC, NG), NC, 0, stream>>>(Woff1, Wvoff, Wcomb_t);

  gemm16_k<<<dim3(NB * NN / 16, 1), 384, 0, stream>>>(q, NC, 0, 0, Wt_all + OFF_WQ, 0, nullptr,
                                                      qp, 0);
  knn2_k<<<NB * (NN / 4), 256, 0, stream>>>(q_pos, v_pos, knn_idx);
  gemm16_k<<<dim3(NB * NN / 16, 2), 384, 0, stream>>>(qp, NGC, 0, NGC, Wt_all + OFF_W1B, 0,
                                                      nullptr, qcontrib, QSZ);
  vproj_k<<<dim3(NB * NM / 16, 6), 384, 0, stream>>>(v, Wcomb_t, Wt_all, vcontrib, KcT, VcT);

  mlp3nn_k<<<NB * NG * NN * NK / 8, 256, 0, stream>>>(vcontrib, qcontrib, boff1, ln_g, ln_b,
                                                      Woff2, knn_idx, v_pos, idx3, w3);
  attn_k<<<NB * NN, NC, 0, stream>>>(qp, KcT, VcT, idx3, w3, attn_out);
  gemm16_k<<<dim3(NB * NN / 16, 1), 384, 0, stream>>>(attn_out, NC, 0, 0, Wt_all + OFF_WPROJ, 0,
                                                      bproj, out, 0);
}

// Round 10
// 463.196 us; speedup vs baseline: 1.1458x; 1.0297x over previous
//
#include <hip/hip_runtime.h>
#include <math.h>

#define NB 4
#define NN 1024
#define NM 1024
#define NC 384
#define NK 10
#define NG 2
#define NGC 192
#define NH 6

#define GSZ ((size_t)NB * NM * NC)   // per-g table size (elements)
#define QSZ ((size_t)NB * NN * NC)
#define NCNC ((size_t)NC * NC)

// Wt_all layout (floats)
#define OFF_WQ 0
#define OFF_W1B 147456
#define OFF_WK0 221184
#define OFF_WK1 294912
#define OFF_WV0 368640
#define OFF_WV1 442368
#define OFF_WPROJ 516096
#define WT_ALL_FLOATS 663552

__device__ __forceinline__ float wred_sum(float v) {
#pragma unroll
  for (int m = 32; m >= 1; m >>= 1) v += __shfl_xor(v, m, 64);
  return v;
}

__device__ __forceinline__ ushort f2bf(float x) {  // RNE, finite inputs
  unsigned u = __float_as_uint(x);
  unsigned r = (u + 0x7fffu + ((u >> 16) & 1u)) >> 16;
  return (ushort)r;
}
__device__ __forceinline__ float b2f_lo(unsigned kv) {
  return __uint_as_float(kv << 16);
}
__device__ __forceinline__ float b2f_hi(unsigned kv) {
  return __uint_as_float(kv & 0xffff0000u);
}

// all 7 weight transposes in one launch; blockIdx.y = job
__global__ void transpose_all_k(const float* __restrict__ Wq, const float* __restrict__ Woff1,
                                const float* __restrict__ Wk, const float* __restrict__ Wv,
                                const float* __restrict__ Wproj, float* __restrict__ Wt_all) {
  const float* W;
  int i0, icount, doff;
  switch (blockIdx.y) {
    case 0: W = Wq;    i0 = 0;   icount = NC;  doff = OFF_WQ;    break;
    case 1: W = Woff1; i0 = NGC; icount = NGC; doff = OFF_W1B;   break;
    case 2: W = Wk;    i0 = 0;   icount = NGC; doff = OFF_WK0;   break;
    case 3: W = Wk;    i0 = NGC; icount = NGC; doff = OFF_WK1;   break;
    case 4: W = Wv;    i0 = 0;   icount = NGC; doff = OFF_WV0;   break;
    case 5: W = Wv;    i0 = NGC; icount = NGC; doff = OFF_WV1;   break;
    default: W = Wproj; i0 = 0;  icount = NC;  doff = OFF_WPROJ; break;
  }
  int id = blockIdx.x * 256 + threadIdx.x;
  if (id >= icount * NC) return;
  int o = id % NC;
  int i = id / NC;
  Wt_all[doff + (size_t)i * NC + o] = W[(size_t)o * NC + i0 + i];
}

// Wcomb_t[g][i][o] = sum_j Woff1[o][j] * Wvoff[g*192+j][i]   (j < 192)
__global__ void wcomb_k(const float* __restrict__ Woff1, const float* __restrict__ Wvoff,
                        float* __restrict__ Wcomb_t) {
  int o = blockIdx.x;
  int g = blockIdx.y;
  int i = threadIdx.x;
  __shared__ float w1[NGC];
  if (i < NGC) w1[i] = Woff1[(size_t)o * NC + i];
  __syncthreads();
  float acc = 0.f;
#pragma unroll 4
  for (int j = 0; j < NGC; ++j)
    acc = fmaf(w1[j], Wvoff[(size_t)(g * NGC + j) * NC + i], acc);
  Wcomb_t[((size_t)g * NC + i) * NC + o] = acc;
}

// generic 16-row 4x4 register-blocked GEMM; blockIdx.y = job
__global__ __launch_bounds__(384) void gemm16_k(const float* __restrict__ X, int IN, int xoff0,
                                                int xoff_stride, const float* __restrict__ Wt0,
                                                size_t wstride, const float* __restrict__ bias,
                                                float* __restrict__ Y0, size_t ystride) {
  __shared__ __align__(16) float xs[NC][20];
  int tid = threadIdx.x;
  int og = tid % 96, rg = tid / 96;
  int r0 = blockIdx.x * 16;
  int job = blockIdx.y;
  int xoff = xoff0 + job * xoff_stride;
  const float* Wt = Wt0 + (size_t)job * wstride;
  float* Y = Y0 + (size_t)job * ystride;
  for (int t = tid; t < 16 * IN; t += 384) {
    int r = t / IN, kk = t % IN;
    xs[kk][r] = X[(size_t)(r0 + r) * NC + xoff + kk];
  }
  __syncthreads();
  float acc[4][4];
#pragma unroll
  for (int i = 0; i < 4; ++i)
#pragma unroll
    for (int j = 0; j < 4; ++j) acc[i][j] = 0.f;
  int o = og * 4;
#pragma unroll 4
  for (int kk = 0; kk < IN; ++kk) {
    float4 w4 = *(const float4*)&Wt[(size_t)kk * NC + o];
    float4 x4 = *(const float4*)&xs[kk][rg * 4];
    float xr[4] = {x4.x, x4.y, x4.z, x4.w};
    float wr[4] = {w4.x, w4.y, w4.z, w4.w};
#pragma unroll
    for (int ri = 0; ri < 4; ++ri)
#pragma unroll
      for (int oi = 0; oi < 4; ++oi) acc[ri][oi] = fmaf(xr[ri], wr[oi], acc[ri][oi]);
  }
  float4 bv = make_float4(0.f, 0.f, 0.f, 0.f);
  if (bias) bv = *(const float4*)&bias[o];
#pragma unroll
  for (int ri = 0; ri < 4; ++ri) {
    float4 ov;
    ov.x = acc[ri][0] + bv.x;
    ov.y = acc[ri][1] + bv.y;
    ov.z = acc[ri][2] + bv.z;
    ov.w = acc[ri][3] + bv.w;
    *(float4*)&Y[(size_t)(r0 + rg * 4 + ri) * NC + o] = ov;
  }
}

// v projections, blockIdx.y = job:
//  0,1: vcontrib g0/g1 = v @ Wcomb[g]  (f32, IN=384)
//  2,3: KV g0/g1: K = v_slice @ WkT[g], V = v_slice @ WvT[g] (IN=192 each),
//       packed interleaved as uint (lo16=K bf16, hi16=V bf16)
__global__ __launch_bounds__(384) void vproj_k(const float* __restrict__ v,
                                               const float* __restrict__ Wcomb_t,
                                               const float* __restrict__ Wt_all,
                                               float* __restrict__ vcontrib,
                                               unsigned* __restrict__ KVc) {
  __shared__ __align__(16) float xs[NC][20];
  int tid = threadIdx.x;
  int og = tid % 96, rg = tid / 96;
  int r0 = blockIdx.x * 16;
  int job = blockIdx.y;
  int o = og * 4;
  if (job < 2) {
    const float* Wt = job ? (Wcomb_t + NCNC) : Wcomb_t;
    float* Yf = job ? (vcontrib + GSZ) : vcontrib;
    for (int t = tid; t < 16 * NC; t += 384) {
      int r = t / NC, kk = t % NC;
      xs[kk][r] = v[(size_t)(r0 + r) * NC + kk];
    }
    __syncthreads();
    float acc[4][4];
#pragma unroll
    for (int i = 0; i < 4; ++i)
#pragma unroll
      for (int j = 0; j < 4; ++j) acc[i][j] = 0.f;
#pragma unroll 4
    for (int kk = 0; kk < NC; ++kk) {
      float4 w4 = *(const float4*)&Wt[(size_t)kk * NC + o];
      float4 x4 = *(const float4*)&xs[kk][rg * 4];
      float xr[4] = {x4.x, x4.y, x4.z, x4.w};
      float wr[4] = {w4.x, w4.y, w4.z, w4.w};
#pragma unroll
      for (int ri = 0; ri < 4; ++ri)
#pragma unroll
        for (int oi = 0; oi < 4; ++oi) acc[ri][oi] = fmaf(xr[ri], wr[oi], acc[ri][oi]);
    }
#pragma unroll
    for (int ri = 0; ri < 4; ++ri)
      *(float4*)&Yf[(size_t)(r0 + rg * 4 + ri) * NC + o] =
          make_float4(acc[ri][0], acc[ri][1], acc[ri][2], acc[ri][3]);
  } else {
    int g = job - 2;
    int xoff = g * NGC;
    const float* WtK = Wt_all + (g ? OFF_WK1 : OFF_WK0);
    const float* WtV = Wt_all + (g ? OFF_WV1 : OFF_WV0);
    unsigned* Yu = KVc + (size_t)g * GSZ;
    for (int t = tid; t < 16 * NGC; t += 384) {
      int r = t / NGC, kk = t % NGC;
      xs[kk][r] = v[(size_t)(r0 + r) * NC + xoff + kk];
    }
    __syncthreads();
    float aK[4][4], aV[4][4];
#pragma unroll
    for (int i = 0; i < 4; ++i)
#pragma unroll
      for (int j = 0; j < 4; ++j) { aK[i][j] = 0.f; aV[i][j] = 0.f; }
#pragma unroll 2
    for (int kk = 0; kk < NGC; ++kk) {
      float4 wk = *(const float4*)&WtK[(size_t)kk * NC + o];
      float4 wv = *(const float4*)&WtV[(size_t)kk * NC + o];
      float4 x4 = *(const float4*)&xs[kk][rg * 4];
      float xr[4] = {x4.x, x4.y, x4.z, x4.w};
      float wkr[4] = {wk.x, wk.y, wk.z, wk.w};
      float wvr[4] = {wv.x, wv.y, wv.z, wv.w};
#pragma unroll
      for (int ri = 0; ri < 4; ++ri)
#pragma unroll
        for (int oi = 0; oi < 4; ++oi) {
          aK[ri][oi] = fmaf(xr[ri], wkr[oi], aK[ri][oi]);
          aV[ri][oi] = fmaf(xr[ri], wvr[oi], aV[ri][oi]);
        }
    }
#pragma unroll
    for (int ri = 0; ri < 4; ++ri) {
      uint4 pk;
      pk.x = (unsigned)f2bf(aK[ri][0]) | ((unsigned)f2bf(aV[ri][0]) << 16);
      pk.y = (unsigned)f2bf(aK[ri][1]) | ((unsigned)f2bf(aV[ri][1]) << 16);
      pk.z = (unsigned)f2bf(aK[ri][2]) | ((unsigned)f2bf(aV[ri][2]) << 16);
      pk.w = (unsigned)f2bf(aK[ri][3]) | ((unsigned)f2bf(aV[ri][3]) << 16);
      *(uint4*)&Yu[(size_t)(r0 + rg * 4 + ri) * NC + o] = pk;
    }
  }
}

// wave-per-query KNN: lane scans 16 candidates -> register top-10 -> argmin-merge
__global__ __launch_bounds__(256) void knn2_k(const float* __restrict__ q_pos,
                                              const float* __restrict__ v_pos,
                                              int* __restrict__ knn_idx) {
  __shared__ float4 cpos[NM];
  int tid = threadIdx.x, lane = tid & 63, wid = tid >> 6;
  int b = blockIdx.x / (NN / 4);
  int n = (blockIdx.x % (NN / 4)) * 4 + wid;
  for (int t = tid; t < NM; t += 256) {
    float x = v_pos[((size_t)b * NM + t) * 3 + 0];
    float y = v_pos[((size_t)b * NM + t) * 3 + 1];
    float z = v_pos[((size_t)b * NM + t) * 3 + 2];
    cpos[t] = make_float4(x, y, z, x * x + y * y + z * z);
  }
  __syncthreads();
  float qx = q_pos[((size_t)b * NN + n) * 3 + 0];
  float qy = q_pos[((size_t)b * NN + n) * 3 + 1];
  float qz = q_pos[((size_t)b * NN + n) * 3 + 2];
  float qq = qx * qx + qy * qy + qz * qz;
  float bd[NK];
  int bi[NK];
#pragma unroll
  for (int j = 0; j < NK; ++j) { bd[j] = 1e30f; bi[j] = 0x7fffffff; }
#pragma unroll
  for (int t = 0; t < NM / 64; ++t) {
    int m = t * 64 + lane;
    float4 cc = cpos[m];
    float d = qq + cc.w - 2.f * (qx * cc.x + qy * cc.y + qz * cc.z);
    if (d < bd[NK - 1]) {
#pragma unroll
      for (int j = NK - 1; j > 0; --j) {
        if (d < bd[j - 1]) { bd[j] = bd[j - 1]; bi[j] = bi[j - 1]; }
        else if (d < bd[j]) { bd[j] = d; bi[j] = m; }
      }
      if (d < bd[0]) { bd[0] = d; bi[0] = m; }
    }
  }
  size_t base = ((size_t)b * NN + n) * NK;
#pragma unroll
  for (int round = 0; round < NK; ++round) {
    float dh = bd[0];
    int mh = bi[0];
#pragma unroll
    for (int off = 32; off >= 1; off >>= 1) {
      float od = __shfl_xor(dh, off, 64);
      int om = __shfl_xor(mh, off, 64);
      if (od < dh || (od == dh && om < mh)) { dh = od; mh = om; }
    }
    if (lane == 0) knn_idx[base + round] = mh;
    if (bi[0] == mh) {
#pragma unroll
      for (int j = 0; j < NK - 1; ++j) { bd[j] = bd[j + 1]; bi[j] = bi[j + 1]; }
      bd[NK - 1] = 1e30f; bi[NK - 1] = 0x7fffffff;
    }
  }
}

// fused MLP + three_nn: one wave per TWO rows (same b,g,n; k even/odd pair);
// shared qcontrib row; med3 branchless top-3 insert; interleaved butterflies.
__global__ __launch_bounds__(256) void mlp3nn_k(
    const float* __restrict__ vcontrib, const float* __restrict__ qcontrib,
    const float* __restrict__ boff1, const float* __restrict__ ln_g,
    const float* __restrict__ ln_b, const float* __restrict__ Woff2,
    const int* __restrict__ knn_idx, const float* __restrict__ v_pos,
    int* __restrict__ idx3, float* __restrict__ w3) {
  __shared__ float4 cpos[NM];
  int tid = threadIdx.x, lane = tid & 63, wid = tid >> 6;
  int ra = blockIdx.x * 8 + wid * 2;
  int rb = ra + 1;
  int b = (blockIdx.x * 8) / (NK * NN * NG);  // uniform per block
  for (int t = tid; t < NM; t += 256) {
    float x = v_pos[((size_t)b * NM + t) * 3 + 0];
    float y = v_pos[((size_t)b * NM + t) * 3 + 1];
    float z = v_pos[((size_t)b * NM + t) * 3 + 2];
    cpos[t] = make_float4(x, y, z, x * x + y * y + z * z);
  }
  __syncthreads();
  // ra even -> ka even, kb=ka+1, same (b,g,n) for both rows
  int ka = ra % NK;
  int na = (ra / NK) % NN;
  int ga = (ra / (NK * NN)) % NG;
  int ma = knn_idx[((size_t)b * NN + na) * NK + ka];
  int mb = knn_idx[((size_t)b * NN + na) * NK + ka + 1];
  const float* vca = vcontrib + ((size_t)(ga * NB + b) * NM + ma) * NC;
  const float* vcb = vcontrib + ((size_t)(ga * NB + b) * NM + mb) * NC;
  const float* qca = qcontrib + ((size_t)(ga * NB + b) * NN + na) * NC;
  float ha[6], hb[6];
  float sa = 0.f, s2a = 0.f, sb = 0.f, s2b = 0.f;
#pragma unroll
  for (int j = 0; j < 6; ++j) {
    int c = j * 64 + lane;
    float qj = qca[c];
    float bo = boff1[c];
    float xa = vca[c] + qj + bo;
    float xb = vcb[c] + qj + bo;
    ha[j] = xa; sa += xa; s2a += xa * xa;
    hb[j] = xb; sb += xb; s2b += xb * xb;
  }
#pragma unroll
  for (int off = 32; off >= 1; off >>= 1) {
    sa += __shfl_xor(sa, off, 64);
    s2a += __shfl_xor(s2a, off, 64);
    sb += __shfl_xor(sb, off, 64);
    s2b += __shfl_xor(s2b, off, 64);
  }
  float meana = sa * (1.f / NC), meanb = sb * (1.f / NC);
  float vara = s2a * (1.f / NC) - meana * meana;
  float varb = s2b * (1.f / NC) - meanb * meanb;
  float inva = 1.f / sqrtf(vara + 1e-5f);
  float invb = 1.f / sqrtf(varb + 1e-5f);
  float p0a = 0.f, p1a = 0.f, p2a = 0.f, p0b = 0.f, p1b = 0.f, p2b = 0.f;
#pragma unroll
  for (int j = 0; j < 6; ++j) {
    int c = j * 64 + lane;
    float gg = ln_g[c], bb = ln_b[c];
    float w0 = Woff2[0 * NC + c], w1 = Woff2[1 * NC + c], w2 = Woff2[2 * NC + c];
    float xa = (ha[j] - meana) * inva * gg + bb;
    xa = 0.5f * xa * (1.f + erff(xa * 0.70710678118654752f));
    float xb = (hb[j] - meanb) * invb * gg + bb;
    xb = 0.5f * xb * (1.f + erff(xb * 0.70710678118654752f));
    p0a = fmaf(xa, w0, p0a); p1a = fmaf(xa, w1, p1a); p2a = fmaf(xa, w2, p2a);
    p0b = fmaf(xb, w0, p0b); p1b = fmaf(xb, w1, p1b); p2b = fmaf(xb, w2, p2b);
  }
#pragma unroll
  for (int off = 32; off >= 1; off >>= 1) {
    p0a += __shfl_xor(p0a, off, 64);
    p1a += __shfl_xor(p1a, off, 64);
    p2a += __shfl_xor(p2a, off, 64);
    p0b += __shfl_xor(p0b, off, 64);
    p1b += __shfl_xor(p1b, off, 64);
    p2b += __shfl_xor(p2b, off, 64);
  }
  float4 cma = cpos[ma], cmb = cpos[mb];
  float sxa = cma.x + tanhf(p0a), sya = cma.y + tanhf(p1a), sza = cma.z + tanhf(p2a);
  float sxb = cmb.x + tanhf(p0b), syb = cmb.y + tanhf(p1b), szb = cmb.z + tanhf(p2b);
  float qqa = sxa * sxa + sya * sya + sza * sza;
  float qqb = sxb * sxb + syb * syb + szb * szb;
  float d0a = 1e30f, d1a = 1e30f, d2a = 1e30f;
  float d0b = 1e30f, d1b = 1e30f, d2b = 1e30f;
  int i0a = 0x7fffffff, i1a = 0x7fffffff, i2a = 0x7fffffff;
  int i0b = 0x7fffffff, i1b = 0x7fffffff, i2b = 0x7fffffff;
#pragma unroll 4
  for (int t = 0; t < NM / 64; ++t) {
    int m2 = t * 64 + lane;
    float4 cc = cpos[m2];
    float da = qqa + cc.w - 2.f * (sxa * cc.x + sya * cc.y + sza * cc.z);
    float db = qqb + cc.w - 2.f * (sxb * cc.x + syb * cc.y + szb * cc.z);
    // branchless sorted-3 insert; strict < (equal d keeps earlier index).
    // med3 forms compute the exact same values as the min/max network.
    float nd0a = fminf(da, d0a);
    float nd1a = __builtin_amdgcn_fmed3f(da, d0a, d1a);
    float nd2a = __builtin_amdgcn_fmed3f(da, d1a, d2a);
    i2a = (da < d1a) ? i1a : ((da < d2a) ? m2 : i2a);
    i1a = (da < d0a) ? i0a : ((da < d1a) ? m2 : i1a);
    i0a = (da < d0a) ? m2 : i0a;
    d0a = nd0a; d1a = nd1a; d2a = nd2a;
    float nd0b = fminf(db, d0b);
    float nd1b = __builtin_amdgcn_fmed3f(db, d0b, d1b);
    float nd2b = __builtin_amdgcn_fmed3f(db, d1b, d2b);
    i2b = (db < d1b) ? i1b : ((db < d2b) ? m2 : i2b);
    i1b = (db < d0b) ? i0b : ((db < d1b) ? m2 : i1b);
    i0b = (db < d0b) ? m2 : i0b;
    d0b = nd0b; d1b = nd1b; d2b = nd2b;
  }
  float rda[3], rdb[3];
  int rma[3], rmb[3];
#pragma unroll
  for (int round = 0; round < 3; ++round) {
    float dha = d0a; int mha = i0a;
    float dhb = d0b; int mhb = i0b;
#pragma unroll
    for (int off = 32; off >= 1; off >>= 1) {
      float oda = __shfl_xor(dha, off, 64); int oma = __shfl_xor(mha, off, 64);
      float odb = __shfl_xor(dhb, off, 64); int omb = __shfl_xor(mhb, off, 64);
      if (oda < dha || (oda == dha && oma < mha)) { dha = oda; mha = oma; }
      if (odb < dhb || (odb == dhb && omb < mhb)) { dhb = odb; mhb = omb; }
    }
    rda[round] = dha; rma[round] = mha;
    rdb[round] = dhb; rmb[round] = mhb;
    if (i0a == mha) { d0a = d1a; i0a = i1a; d1a = d2a; i1a = i2a; d2a = 1e30f; i2a = 0x7fffffff; }
    if (i0b == mhb) { d0b = d1b; i0b = i1b; d1b = d2b; i1b = i2b; d2b = 1e30f; i2b = 0x7fffffff; }
  }
  if (lane == 0) {
    float e0 = 1.f / (sqrtf(fmaxf(rda[0], 0.f)) + 1e-8f);
    float e1 = 1.f / (sqrtf(fmaxf(rda[1], 0.f)) + 1e-8f);
    float e2 = 1.f / (sqrtf(fmaxf(rda[2], 0.f)) + 1e-8f);
    float sw = e0 + e1 + e2;
    idx3[(size_t)ra * 3 + 0] = rma[0]; w3[(size_t)ra * 3 + 0] = e0 / sw;
    idx3[(size_t)ra * 3 + 1] = rma[1]; w3[(size_t)ra * 3 + 1] = e1 / sw;
    idx3[(size_t)ra * 3 + 2] = rma[2]; w3[(size_t)ra * 3 + 2] = e2 / sw;
    float f0 = 1.f / (sqrtf(fmaxf(rdb[0], 0.f)) + 1e-8f);
    float f1 = 1.f / (sqrtf(fmaxf(rdb[1], 0.f)) + 1e-8f);
    float f2 = 1.f / (sqrtf(fmaxf(rdb[2], 0.f)) + 1e-8f);
    float sw2 = f0 + f1 + f2;
    idx3[(size_t)rb * 3 + 0] = rmb[0]; w3[(size_t)rb * 3 + 0] = f0 / sw2;
    idx3[(size_t)rb * 3 + 1] = rmb[1]; w3[(size_t)rb * 3 + 1] = f1 / sw2;
    idx3[(size_t)rb * 3 + 2] = rmb[2]; w3[(size_t)rb * 3 + 2] = f2 / sw2;
  }
}

// one block per (b,n): gathered kf/vf from the PACKED KV table (one uint load
// yields both bf16 K and V); serial per-k loop, LDS vfs, small reg footprint.
__global__ __launch_bounds__(NC) void attn_k(const float* __restrict__ qp,
                                             const unsigned* __restrict__ KV,
                                             const int* __restrict__ idx3,
                                             const float* __restrict__ w3,
                                             float* __restrict__ attn_out) {
  __shared__ float vfs[NK][NC];
  __shared__ float lgs[NH][NK];
  __shared__ int il[NG][NK][3];
  __shared__ float wl[NG][NK][3];
  int o = threadIdx.x;
  int lane = o & 63, wid = o >> 6;
  int b = blockIdx.x / NN;
  int n = blockIdx.x % NN;
  if (o < NG * NK * 3) {
    int g = o / (NK * 3), k = (o / 3) % NK, j = o % 3;
    size_t rr = (((size_t)(b * NG + g) * NN + n) * NK + k) * 3 + j;
    il[g][k][j] = idx3[rr];
    wl[g][k][j] = w3[rr];
  }
  __syncthreads();
  float qv = qp[((size_t)b * NN + n) * NC + o];
  for (int k = 0; k < NK; ++k) {
    float kf = 0.f, vf = 0.f;
#pragma unroll
    for (int g = 0; g < NG; ++g)
#pragma unroll
      for (int j = 0; j < 3; ++j) {
        int m = il[g][k][j];
        float w = wl[g][k][j];
        unsigned kv = KV[((size_t)(g * NB + b) * NM + m) * NC + o];
        kf = fmaf(w, b2f_lo(kv), kf);
        vf = fmaf(w, b2f_hi(kv), vf);
      }
    vfs[k][o] = vf;
    float p = wred_sum(qv * kf);
    if (lane == 0) lgs[wid][k] = p * 0.125f;
  }
  __syncthreads();
  float a[NK];
  float mx = -1e30f;
#pragma unroll
  for (int k = 0; k < NK; ++k) { a[k] = lgs[wid][k]; mx = fmaxf(mx, a[k]); }
  float sum = 0.f;
#pragma unroll
  for (int k = 0; k < NK; ++k) { a[k] = expf(a[k] - mx); sum += a[k]; }
  float outv = 0.f;
#pragma unroll
  for (int k = 0; k < NK; ++k) outv = fmaf(a[k] / sum, vfs[k][o], outv);
  attn_out[((size_t)b * NN + n) * NC + o] = outv;
}

extern "C" void kernel_launch(void* const* d_in, const int* in_sizes, int n_in,
                              void* d_out, int out_size, void* d_ws, size_t ws_size,
                              hipStream_t stream) {
  (void)in_sizes; (void)n_in; (void)out_size; (void)ws_size;
  const float* q     = (const float*)d_in[0];
  const float* q_pos = (const float*)d_in[1];
  const float* v     = (const float*)d_in[2];
  const float* v_pos = (const float*)d_in[3];
  const float* Wq    = (const float*)d_in[4];
  const float* Wk    = (const float*)d_in[5];
  const float* Wv    = (const float*)d_in[6];
  const float* Wvoff = (const float*)d_in[7];
  const float* Woff1 = (const float*)d_in[8];
  const float* boff1 = (const float*)d_in[9];
  const float* ln_g  = (const float*)d_in[10];
  const float* ln_b  = (const float*)d_in[11];
  const float* Woff2 = (const float*)d_in[12];
  const float* Wproj = (const float*)d_in[13];
  const float* bproj = (const float*)d_in[14];
  float* out = (float*)d_out;

  char* p = (char*)d_ws;
  auto alloc_f = [&](size_t n) { float* r = (float*)p; p += n * sizeof(float); return r; };
  auto alloc_u = [&](size_t n) { unsigned* r = (unsigned*)p; p += n * sizeof(unsigned); return r; };
  auto alloc_i = [&](size_t n) { int* r = (int*)p; p += n * sizeof(int); return r; };

  float* qp        = alloc_f(QSZ);
  float* qcontrib  = alloc_f((size_t)NG * QSZ);
  float* vcontrib  = alloc_f((size_t)NG * GSZ);
  float* Wt_all    = alloc_f((size_t)WT_ALL_FLOATS);
  float* Wcomb_t   = alloc_f((size_t)NG * NCNC);
  float* w3        = alloc_f((size_t)NB * NG * NN * NK * 3);
  unsigned* KVc    = alloc_u((size_t)NG * GSZ);
  int* knn_idx     = alloc_i((size_t)NB * NN * NK);
  int* idx3        = alloc_i((size_t)NB * NG * NN * NK * 3);
  float* attn_out  = vcontrib;  // vcontrib dead after mlp3nn_k; reuse

  transpose_all_k<<<dim3(576, 7), 256, 0, stream>>>(Wq, Woff1, Wk, Wv, Wproj, Wt_all);
  wcomb_k<<<dim3(NC, NG), NC, 0, stream>>>(Woff1, Wvoff, Wcomb_t);

  gemm16_k<<<dim3(NB * NN / 16, 1), 384, 0, stream>>>(q, NC, 0, 0, Wt_all + OFF_WQ, 0, nullptr,
                                                      qp, 0);
  knn2_k<<<NB * (NN / 4), 256, 0, stream>>>(q_pos, v_pos, knn_idx);
  gemm16_k<<<dim3(NB * NN / 16, 2), 384, 0, stream>>>(qp, NGC, 0, NGC, Wt_all + OFF_W1B, 0,
                                                      nullptr, qcontrib, QSZ);
  vproj_k<<<dim3(NB * NM / 16, 4), 384, 0, stream>>>(v, Wcomb_t, Wt_all, vcontrib, KVc);

  mlp3nn_k<<<NB * NG * NN * NK / 8, 256, 0, stream>>>(vcontrib, qcontrib, boff1, ln_g, ln_b,
                                                      Woff2, knn_idx, v_pos, idx3, w3);
  attn_k<<<NB * NN, NC, 0, stream>>>(qp, KVc, idx3, w3, attn_out);
  gemm16_k<<<dim3(NB * NN / 16, 1), 384, 0, stream>>>(attn_out, NC, 0, 0, Wt_all + OFF_WPROJ, 0,
                                                      bproj, out, 0);
}